// Round 4
// baseline (672.033 us; speedup 1.0000x reference)
//
#include <hip/hip_runtime.h>
#include <hip/hip_bf16.h>
#include <math.h>

// Problem constants: B=4, S=2048, D=4096, 2B*S = 16384 rows.
#define PAD_ID 50256
#define S_LEN 2048
#define B_PAIRS 4
#define D4_C 1024          // D/4

// Fused kernel: GEMV (all blocks) + ids scans (block 0, overlapped) +
// scores/loss tail (last block to finish, via atomic completion counter).
// No spin-waits: every block atomically increments and exits; exactly the
// last one runs the tail — safe under any dispatch order / occupancy.
//
// d_ws layout: ws[0] = completion counter (zeroed by hipMemsetAsync each call),
//              ws[2+2b] = div_ind(pair b), ws[3+2b] = end_ind(pair b).
// d_out layout: out[0]=loss, out[1..16384]=rewards,
//               out[16385+b]=chosen_mean, +4 rejected_mean,
//               +8 chosen_end, +12 rejected_end.

__device__ inline float wave_sum_xor(float v) {
    #pragma unroll
    for (int off = 32; off > 0; off >>= 1) v += __shfl_xor(v, off, 64);
    return v;
}
__device__ inline int wave_min_xor(int v) {
    #pragma unroll
    for (int off = 32; off > 0; off >>= 1) v = min(v, __shfl_xor(v, off, 64));
    return v;
}

__global__ __launch_bounds__(256) void fused_kernel(
    const float4* __restrict__ hs,   // (nrows, D/4)
    const float4* __restrict__ w4,   // (D/4,)
    const int*    __restrict__ ids,  // (2B, S)
    float*        __restrict__ out,
    unsigned*     __restrict__ ws,
    int nrows)
{
    float* rew = out + 1;
    const int wave = threadIdx.x >> 6;
    const int lane = threadIdx.x & 63;
    const int row0 = (blockIdx.x * 4 + wave) * 2;

    // w hoisted to 16 float4 regs/lane, reused across 2 rows.
    float4 wv[16];
    #pragma unroll
    for (int k = 0; k < 16; ++k) wv[k] = w4[lane + 64 * k];

    #pragma unroll
    for (int r = 0; r < 2; ++r) {
        const int row = row0 + r;
        if (row < nrows) {
            const float4* rp = hs + (size_t)row * D4_C;
            float acc0 = 0.0f, acc1 = 0.0f;
            #pragma unroll
            for (int k = 0; k < 16; k += 2) {
                float4 a0 = rp[lane + 64 * k];
                float4 a1 = rp[lane + 64 * (k + 1)];
                acc0 = fmaf(a0.x, wv[k].x,     acc0);
                acc0 = fmaf(a0.y, wv[k].y,     acc0);
                acc0 = fmaf(a0.z, wv[k].z,     acc0);
                acc0 = fmaf(a0.w, wv[k].w,     acc0);
                acc1 = fmaf(a1.x, wv[k + 1].x, acc1);
                acc1 = fmaf(a1.y, wv[k + 1].y, acc1);
                acc1 = fmaf(a1.z, wv[k + 1].z, acc1);
                acc1 = fmaf(a1.w, wv[k + 1].w, acc1);
            }
            float acc = acc0 + acc1;
            #pragma unroll
            for (int off = 32; off > 0; off >>= 1)
                acc += __shfl_down(acc, off, 64);
            if (lane == 0) rew[row] = acc;
        }
    }

    // Block 0: ids first-index scans, one wave per pair — overlaps with the
    // other blocks' GEMV work (no dependency on rewards).
    if (blockIdx.x == 0) {
        const int b = wave;                         // B_PAIRS == waves/block
        const int* ch = ids + b * S_LEN;
        const int* rj = ids + (B_PAIRS + b) * S_LEN;
        int ldiv = S_LEN, lc = S_LEN, lr = S_LEN;
        for (int s = lane; s < S_LEN; s += 64) {
            int c = ch[s], r = rj[s];
            if (c != r)      ldiv = min(ldiv, s);
            if (c == PAD_ID) lc   = min(lc, s);
            if (r == PAD_ID) lr   = min(lr, s);
        }
        ldiv = wave_min_xor(ldiv);
        lc   = wave_min_xor(lc);
        lr   = wave_min_xor(lr);
        if (lane == 0) {
            ws[2 + 2 * b] = (unsigned)ldiv;
            ws[3 + 2 * b] = (unsigned)max(lc, lr);
        }
    }

    // Release: make this block's stores device-visible, then count completion.
    __threadfence();
    __syncthreads();
    __shared__ bool is_last;
    if (threadIdx.x == 0)
        is_last = (atomicAdd(ws, 1u) == (unsigned)(gridDim.x - 1));
    __syncthreads();
    if (!is_last) return;
    __threadfence();   // acquire side

    // Tail (last block only): wave b -> pair b means/ends/loss.
    __shared__ float s_loss[B_PAIRS];
    {
        const int b  = wave;
        const int dv = (int)ws[2 + 2 * b];
        const int en = (int)ws[3 + 2 * b];
        const float* cr = rew + b * S_LEN;
        const float* rr = rew + (B_PAIRS + b) * S_LEN;
        float sc = 0.0f, sr = 0.0f, sl = 0.0f;
        for (int s = dv + lane; s < en; s += 64) {
            float cv = cr[s], rv = rr[s];
            sc += cv;
            sr += rv;
            float x = cv - rv;
            // -log_sigmoid(x) = softplus(-x), stable form
            sl += fmaxf(-x, 0.0f) + log1pf(expf(-fabsf(x)));
        }
        sc = wave_sum_xor(sc);
        sr = wave_sum_xor(sr);
        sl = wave_sum_xor(sl);
        if (lane == 0) {
            int   cnt = max(en - dv, 1);
            float inv = 1.0f / (float)cnt;
            int  last = max(en - 1, 0);
            const int base = 1 + 2 * B_PAIRS * S_LEN;   // 16385
            out[base + 0 * B_PAIRS + b] = sc * inv;   // chosen_mean_scores
            out[base + 1 * B_PAIRS + b] = sr * inv;   // rejected_mean_scores
            out[base + 2 * B_PAIRS + b] = cr[last];   // chosen_end_scores
            out[base + 3 * B_PAIRS + b] = rr[last];   // rejected_end_scores
            s_loss[b] = sl * inv;
        }
    }
    __syncthreads();
    if (threadIdx.x == 0)
        out[0] = (s_loss[0] + s_loss[1] + s_loss[2] + s_loss[3]) *
                 (1.0f / (float)B_PAIRS);
}

extern "C" void kernel_launch(void* const* d_in, const int* in_sizes, int n_in,
                              void* d_out, int out_size, void* d_ws, size_t ws_size,
                              hipStream_t stream) {
    const float* hs  = (const float*)d_in[0];   // (2B, S, D) fp32
    const float* w   = (const float*)d_in[1];   // (D,) fp32
    const int*   ids = (const int*)d_in[2];     // (2B, S) int

    float*    out = (float*)d_out;
    unsigned* ws  = (unsigned*)d_ws;

    const int nrows = in_sizes[0] / in_sizes[1];   // 16384
    const int rows_per_block = 4 * 2;              // 4 waves x 2 rows
    const int blocks = (nrows + rows_per_block - 1) / rows_per_block;  // 2048

    // Zero the completion counter (graph-capture-safe, stream-ordered).
    hipMemsetAsync(ws, 0, sizeof(unsigned), stream);

    fused_kernel<<<blocks, 256, 0, stream>>>(
        (const float4*)hs, (const float4*)w, ids, out, ws, nrows);
}

// Round 5
// 386.506 us; speedup vs baseline: 1.7387x; 1.7387x over previous
//
#include <hip/hip_runtime.h>
#include <hip/hip_bf16.h>
#include <math.h>

// Problem constants: B=4, S=2048, D=4096, 2B*S = 16384 rows.
#define PAD_ID 50256
#define S_LEN 2048
#define B_PAIRS 4
#define D4_C 1024          // D/4

// ---------------------------------------------------------------------------
// Kernel 1: rewards[row] = dot(hidden_states[row,:], w)
// 256-thread blocks (4 waves). w staged in LDS once per block (16 KB,
// ds_read pipe — keeps the VMEM queue pure hs stream, VGPRs low).
// Each wave owns 4 rows, processed 2-at-a-time CONCURRENTLY: 32 independent
// float4 loads in flight per wave before the FMA chain. 1024 blocks.
// NOTE (R4 post-mortem): no cross-block fences/atomics — device-scope
// __threadfence per block forced L2 writebacks on the 8-XCD hierarchy and
// cost +290 us. Two plain kernels are strictly better here.
// ---------------------------------------------------------------------------
__global__ __launch_bounds__(256) void rewards_kernel(
    const float4* __restrict__ hs,   // (nrows, D/4)
    const float4* __restrict__ w4,   // (D/4,)
    float* __restrict__ rew,         // (nrows,) == d_out + 1
    int nrows)
{
    __shared__ float4 sw[D4_C];      // 16 KB
    #pragma unroll
    for (int i = 0; i < 4; ++i)
        sw[threadIdx.x + 256 * i] = w4[threadIdx.x + 256 * i];
    __syncthreads();

    const int wave = threadIdx.x >> 6;
    const int lane = threadIdx.x & 63;
    const int row0 = (blockIdx.x * 4 + wave) * 4;   // 4 rows per wave

    #pragma unroll
    for (int pr = 0; pr < 2; ++pr) {                // two row-pairs
        const int row = row0 + pr * 2;
        if (row + 1 < nrows) {
            const float4* p0 = hs + (size_t)row * D4_C;
            const float4* p1 = p0 + D4_C;
            float acc0 = 0.0f, acc1 = 0.0f;
            #pragma unroll
            for (int k = 0; k < 16; ++k) {
                float4 a0 = p0[lane + 64 * k];
                float4 a1 = p1[lane + 64 * k];
                float4 wk = sw[lane + 64 * k];      // ds_read_b128, 2-way alias = free
                acc0 = fmaf(a0.x, wk.x, acc0);
                acc0 = fmaf(a0.y, wk.y, acc0);
                acc0 = fmaf(a0.z, wk.z, acc0);
                acc0 = fmaf(a0.w, wk.w, acc0);
                acc1 = fmaf(a1.x, wk.x, acc1);
                acc1 = fmaf(a1.y, wk.y, acc1);
                acc1 = fmaf(a1.z, wk.z, acc1);
                acc1 = fmaf(a1.w, wk.w, acc1);
            }
            #pragma unroll
            for (int off = 32; off > 0; off >>= 1) {
                acc0 += __shfl_xor(acc0, off, 64);
                acc1 += __shfl_xor(acc1, off, 64);
            }
            if (lane == 0) { rew[row] = acc0; rew[row + 1] = acc1; }
        } else if (row < nrows) {                   // tail (not hit at 16384)
            const float4* p0 = hs + (size_t)row * D4_C;
            float acc0 = 0.0f;
            for (int k = 0; k < 16; ++k) {
                float4 a0 = p0[lane + 64 * k];
                float4 wk = sw[lane + 64 * k];
                acc0 = fmaf(a0.x, wk.x, acc0);
                acc0 = fmaf(a0.y, wk.y, acc0);
                acc0 = fmaf(a0.z, wk.z, acc0);
                acc0 = fmaf(a0.w, wk.w, acc0);
            }
            for (int off = 32; off > 0; off >>= 1)
                acc0 += __shfl_xor(acc0, off, 64);
            if (lane == 0) rew[row] = acc0;
        }
    }
}

// ---------------------------------------------------------------------------
// Kernel 2: one wave per pair — ids scan + masked sums + ends + loss, fully
// parallel across the 4 waves of a single block (no inter-wave dependency
// until the final loss mean).
// Output layout: out[0]=loss, out[1..16384]=rewards,
//   out[16385+b]=chosen_mean, +4 rejected_mean, +8 chosen_end, +12 rejected_end
// ---------------------------------------------------------------------------
__device__ inline float wave_sum_xor(float v) {
    #pragma unroll
    for (int off = 32; off > 0; off >>= 1) v += __shfl_xor(v, off, 64);
    return v;
}
__device__ inline int wave_min_xor(int v) {
    #pragma unroll
    for (int off = 32; off > 0; off >>= 1) v = min(v, __shfl_xor(v, off, 64));
    return v;
}

__global__ __launch_bounds__(256) void scores_kernel(
    const float* __restrict__ rew,   // (2B, S) == d_out + 1
    const int*   __restrict__ ids,   // (2B, S)
    float* __restrict__ out)
{
    __shared__ float s_loss[B_PAIRS];
    const int wave = threadIdx.x >> 6;
    const int lane = threadIdx.x & 63;
    const int b    = wave;           // 4 waves == B_PAIRS

    const int*   ch = ids + b * S_LEN;
    const int*   rj = ids + (B_PAIRS + b) * S_LEN;
    const float* cr = rew + b * S_LEN;
    const float* rr = rew + (B_PAIRS + b) * S_LEN;

    // first-index scans
    int ldiv = S_LEN, lc = S_LEN, lr = S_LEN;
    for (int s = lane; s < S_LEN; s += 64) {
        int c = ch[s], r = rj[s];
        if (c != r)      ldiv = min(ldiv, s);
        if (c == PAD_ID) lc   = min(lc, s);
        if (r == PAD_ID) lr   = min(lr, s);
    }
    const int dv = wave_min_xor(ldiv);
    const int en = max(wave_min_xor(lc), wave_min_xor(lr));

    // masked sums over [dv, en)
    float sc = 0.0f, sr = 0.0f, sl = 0.0f;
    for (int s = dv + lane; s < en; s += 64) {
        float cv = cr[s], rv = rr[s];
        sc += cv;
        sr += rv;
        float x = cv - rv;
        // -log_sigmoid(x) = softplus(-x), numerically stable
        sl += fmaxf(-x, 0.0f) + log1pf(expf(-fabsf(x)));
    }
    sc = wave_sum_xor(sc);
    sr = wave_sum_xor(sr);
    sl = wave_sum_xor(sl);

    if (lane == 0) {
        int   cnt = max(en - dv, 1);
        float inv = 1.0f / (float)cnt;
        int  last = max(en - 1, 0);
        const int base = 1 + 2 * B_PAIRS * S_LEN;   // 16385
        out[base + 0 * B_PAIRS + b] = sc * inv;   // chosen_mean_scores
        out[base + 1 * B_PAIRS + b] = sr * inv;   // rejected_mean_scores
        out[base + 2 * B_PAIRS + b] = cr[last];   // chosen_end_scores
        out[base + 3 * B_PAIRS + b] = rr[last];   // rejected_end_scores
        s_loss[b] = sl * inv;
    }
    __syncthreads();
    if (threadIdx.x == 0)
        out[0] = (s_loss[0] + s_loss[1] + s_loss[2] + s_loss[3]) *
                 (1.0f / (float)B_PAIRS);
}

extern "C" void kernel_launch(void* const* d_in, const int* in_sizes, int n_in,
                              void* d_out, int out_size, void* d_ws, size_t ws_size,
                              hipStream_t stream) {
    const float* hs  = (const float*)d_in[0];   // (2B, S, D) fp32
    const float* w   = (const float*)d_in[1];   // (D,) fp32
    const int*   ids = (const int*)d_in[2];     // (2B, S) int

    float* out = (float*)d_out;
    float* rew = out + 1;

    const int nrows = in_sizes[0] / in_sizes[1];       // 16384
    const int rows_per_block = 16;                     // 4 waves x 4 rows
    const int blocks = (nrows + rows_per_block - 1) / rows_per_block;  // 1024

    rewards_kernel<<<blocks, 256, 0, stream>>>(
        (const float4*)hs, (const float4*)w, rew, nrows);

    scores_kernel<<<1, 256, 0, stream>>>(rew, ids, out);
}